// Round 9
// baseline (2126.556 us; speedup 1.0000x reference)
//
#include <hip/hip_runtime.h>
#include <hip/hip_bf16.h>
#include <cstdint>

// B=8, C=256, N=4096 spatial self-attention.
// R13: occupancy unlock. rocprof shows VGPR=128 -> register limit allows
// 4 waves/SIMD (pool ~512/SIMD, m69); LDS 132KB was the real 1-block/CU cap.
// attn: 1024 blocks (b, qtile, key-QUARTER) x 256 thr (4 waves x 32 q),
// 32 KB LDS (single K|V buffer, split-phase staging cadence from R11:
// qk -> bar -> stageK(it+1) -> sm -> PV -> bar -> stageV(it+1)), 32 iters.
// => 4 blocks/CU, 16 waves/CU, FOUR independent barrier domains.
// Cross-block merge of the 4 quarters per (b,qtile): device-scope ticket
// chain through `out` (arrival ticket via atomicAdd; ticket k spins on
// flag==k, rescale-merges O/l/m; ticket 3 normalizes + gamma + residual).
// Deadlock-free: spinner's predecessor already passed the atomic; grid ==
// residency capacity. Meta zeroed each launch by wcvt (stream order).
// Keeps: V-read rotation (0 conflicts), swapped QK^T w/ lane-local P, DPP
// wave-max, defer-rescale THR=8, Q/V pair-interleave, XOR K staging, 3-pass qkv.

typedef short short8 __attribute__((ext_vector_type(8)));
typedef short short4v __attribute__((ext_vector_type(4)));
typedef float f32x4 __attribute__((ext_vector_type(4)));
typedef unsigned int uint4v __attribute__((ext_vector_type(4)));

#define MFMA16(a, b, c) __builtin_amdgcn_mfma_f32_16x16x32_bf16((a), (b), (c), 0, 0, 0)
#define LOG2E 1.4426950408889634f

__device__ __forceinline__ unsigned short f2bf(float f) {
    union { float f; unsigned int u; } v;
    v.f = f;
    unsigned int u = v.u;
    return (unsigned short)((u + 0x7fffu + ((u >> 16) & 1u)) >> 16);
}

__device__ __forceinline__ void load_lds16(const unsigned short* g, unsigned short* l) {
    __builtin_amdgcn_global_load_lds(
        (const __attribute__((address_space(1))) unsigned int*)g,
        (__attribute__((address_space(3))) unsigned int*)l, 16, 0, 0);
}

// max over the 16-lane row group via DPP row_ror (VALU only, no LDS unit)
__device__ __forceinline__ float rowmax16_dpp(float x) {
    int v;
    v = __builtin_amdgcn_update_dpp(0, __float_as_int(x), 0x121, 0xf, 0xf, false);
    x = fmaxf(x, __int_as_float(v));
    v = __builtin_amdgcn_update_dpp(0, __float_as_int(x), 0x122, 0xf, 0xf, false);
    x = fmaxf(x, __int_as_float(v));
    v = __builtin_amdgcn_update_dpp(0, __float_as_int(x), 0x124, 0xf, 0xf, false);
    x = fmaxf(x, __int_as_float(v));
    v = __builtin_amdgcn_update_dpp(0, __float_as_int(x), 0x128, 0xf, 0xf, false);
    x = fmaxf(x, __int_as_float(v));
    return x;
}

// 16-group maxes -> full-wave max broadcast, VALU-only (row_bcast15/31 + readlane)
__device__ __forceinline__ float wavemax_bcast(float x) {
    int v;
    v = __builtin_amdgcn_update_dpp(__float_as_int(x), __float_as_int(x), 0x142, 0xf, 0xf, false);
    x = fmaxf(x, __int_as_float(v));
    v = __builtin_amdgcn_update_dpp(__float_as_int(x), __float_as_int(x), 0x143, 0xf, 0xf, false);
    x = fmaxf(x, __int_as_float(v));
    return __int_as_float(__builtin_amdgcn_readlane(__float_as_int(x), 63));
}

// ---------------- Kernel 0: weight fp32 -> bf16 + meta zero ------------------
__global__ __launch_bounds__(256) void wcvt_kernel(
    const float* __restrict__ wq, const float* __restrict__ wk,
    const float* __restrict__ wv, unsigned short* __restrict__ Wb,
    int* __restrict__ meta)     // [cnts[256] | flags[256]]
{
    if (blockIdx.x == 0 && threadIdx.x < 256) {
        meta[threadIdx.x] = 0;
        meta[256 + threadIdx.x] = 0;
    }
    int idx = (blockIdx.x * 256 + threadIdx.x) * 4;
    const float* src = (idx < 65536) ? wq : ((idx < 131072) ? wk : wv);
    float4 f = *(const float4*)(src + (idx & 65535));
    short4v s = { (short)f2bf(f.x), (short)f2bf(f.y), (short)f2bf(f.z), (short)f2bf(f.w) };
    *(short4v*)(Wb + idx) = s;
}

// ---------------- Kernel 1: QKV projection via MFMA --------------------------
// 1024 blocks x 256 thr (4 waves). Block: batch b, 32 tokens; wave: 64 channels.
// Three sequential passes (Q, V, K). Qc AND Vc both [B][C][N] bf16,
// pair-interleaved per 32-token chunk: u32 slot a <- tokens (a, a+16).
// Q pre-scaled by log2e. Kr [B][N][C].
__global__ __launch_bounds__(256, 2) void qkv_kernel(
    const float* __restrict__ x, const unsigned short* __restrict__ Wb,
    const float* __restrict__ bq, const float* __restrict__ bk,
    const float* __restrict__ bv,
    unsigned short* __restrict__ Qc, unsigned short* __restrict__ Kr,
    unsigned short* __restrict__ Vc)
{
    const int C = 256, N = 4096;
    __shared__ __align__(16) unsigned short Xt[32][264];   // [token][c], pad 264

    const int tid  = threadIdx.x;
    const int bid  = blockIdx.x;
    const int b    = bid >> 7;
    const int n0   = (bid & 127) * 32;
    const int wave = tid >> 6;
    const int lane = tid & 63;
    const int quad = lane >> 4;
    const int l16  = lane & 15;
    const int ch0  = wave * 64;

    // stage X^T tile: fp32 [c][token] -> bf16 LDS [token][c]
    {
        const int token = tid & 31;
        const int cg    = tid >> 5;
        const float* xb = x + ((size_t)b * C) * N + n0 + token;
#pragma unroll
        for (int p = 0; p < 8; p++) {
            int c0 = p * 32 + cg * 4;
            float f0 = xb[(size_t)(c0 + 0) * N];
            float f1 = xb[(size_t)(c0 + 1) * N];
            float f2 = xb[(size_t)(c0 + 2) * N];
            float f3 = xb[(size_t)(c0 + 3) * N];
            short4v s = { (short)f2bf(f0), (short)f2bf(f1), (short)f2bf(f2), (short)f2bf(f3) };
            *(short4v*)(&Xt[token][c0]) = s;
        }
    }
    __syncthreads();

    f32x4 acc[4][2];

    // ---------------- pass 0: Q (m=0), scaled by log2e, pair-interleaved -----
#pragma unroll
    for (int ct = 0; ct < 4; ct++)
#pragma unroll
        for (int tt = 0; tt < 2; tt++) acc[ct][tt] = (f32x4){0.f, 0.f, 0.f, 0.f};
#pragma unroll
    for (int kc = 0; kc < 8; kc++) {
        const int ko = kc * 32 + quad * 8;
        short8 ax0 = *(const short8*)(&Xt[l16][ko]);
        short8 ax1 = *(const short8*)(&Xt[16 + l16][ko]);
#pragma unroll
        for (int ct = 0; ct < 4; ct++) {
            short8 wf = *(const short8*)(Wb + (ch0 + ct * 16 + l16) * 256 + ko);
            acc[ct][0] = MFMA16(ax0, wf, acc[ct][0]);
            acc[ct][1] = MFMA16(ax1, wf, acc[ct][1]);
        }
    }
#pragma unroll
    for (int ct = 0; ct < 4; ct++) {
        const int ch = ch0 + ct * 16 + l16;
        const float biq = bq[ch];
        uint4v qv;
#pragma unroll
        for (int r = 0; r < 4; r++) {
            unsigned int lo = f2bf((acc[ct][0][r] + biq) * LOG2E);   // token quad*4+r
            unsigned int hi = f2bf((acc[ct][1][r] + biq) * LOG2E);   // token quad*4+r+16
            qv[r] = lo | (hi << 16);
        }
        *(uint4v*)(Qc + ((size_t)b * C + ch) * N + n0 + quad * 8) = qv;
    }

    // ---------------- pass 1: V (m=2), pair-interleaved b128 stores ----------
#pragma unroll
    for (int ct = 0; ct < 4; ct++)
#pragma unroll
        for (int tt = 0; tt < 2; tt++) acc[ct][tt] = (f32x4){0.f, 0.f, 0.f, 0.f};
#pragma unroll
    for (int kc = 0; kc < 8; kc++) {
        const int ko = kc * 32 + quad * 8;
        short8 ax0 = *(const short8*)(&Xt[l16][ko]);
        short8 ax1 = *(const short8*)(&Xt[16 + l16][ko]);
#pragma unroll
        for (int ct = 0; ct < 4; ct++) {
            short8 wf = *(const short8*)(Wb + (2 << 16) + (ch0 + ct * 16 + l16) * 256 + ko);
            acc[ct][0] = MFMA16(ax0, wf, acc[ct][0]);
            acc[ct][1] = MFMA16(ax1, wf, acc[ct][1]);
        }
    }
#pragma unroll
    for (int ct = 0; ct < 4; ct++) {
        const int ch = ch0 + ct * 16 + l16;
        const float biv = bv[ch];
        uint4v vv;
#pragma unroll
        for (int r = 0; r < 4; r++) {
            unsigned int lo = f2bf(acc[ct][0][r] + biv);
            unsigned int hi = f2bf(acc[ct][1][r] + biv);
            vv[r] = lo | (hi << 16);
        }
        *(uint4v*)(Vc + ((size_t)b * C + ch) * N + n0 + quad * 8) = vv;
    }

    // ---------------- pass 2: K (m=1), transpose via LDS ----------------
#pragma unroll
    for (int ct = 0; ct < 4; ct++)
#pragma unroll
        for (int tt = 0; tt < 2; tt++) acc[ct][tt] = (f32x4){0.f, 0.f, 0.f, 0.f};
#pragma unroll
    for (int kc = 0; kc < 8; kc++) {
        const int ko = kc * 32 + quad * 8;
        short8 ax0 = *(const short8*)(&Xt[l16][ko]);
        short8 ax1 = *(const short8*)(&Xt[16 + l16][ko]);
#pragma unroll
        for (int ct = 0; ct < 4; ct++) {
            short8 wf = *(const short8*)(Wb + (1 << 16) + (ch0 + ct * 16 + l16) * 256 + ko);
            acc[ct][0] = MFMA16(ax0, wf, acc[ct][0]);
            acc[ct][1] = MFMA16(ax1, wf, acc[ct][1]);
        }
    }
    __syncthreads();    // Xt reads all done (all passes)
#pragma unroll
    for (int ct = 0; ct < 4; ct++) {
        const int ch = ch0 + ct * 16 + l16;
        const float bik = bk[ch];
#pragma unroll
        for (int tt = 0; tt < 2; tt++) {
#pragma unroll
            for (int r = 0; r < 4; r++)
                Xt[tt * 16 + quad * 4 + r][ch] = f2bf(acc[ct][tt][r] + bik);
        }
    }
    __syncthreads();
#pragma unroll
    for (int p = 0; p < 2; p++) {
        int chunk = p * 256 + tid;          // 0..511
        int tok = chunk >> 4;
        int cc  = (chunk & 15) * 16;
        *(short8*)(Kr + ((size_t)b * N + n0 + tok) * C + cc) = *(const short8*)(&Xt[tok][cc]);
    }
}

// ---------------- Kernel 2: flash attention (quarter-blocks) -----------------
// 1024 blocks x 256 thr (4 waves): quarter = bid&3, b = (bid>>2)&7, qt = bid>>5.
// Wave w: queries q0 = qt*128 + w*32, keys [quarter*1024, +1024), 32 iters.
// LDS 32 KB (K 16 | V 16), split-phase staging. Ticket-chain merge via out.
__global__ __launch_bounds__(256, 4) void attn_kernel(
    const unsigned short* __restrict__ Qc,
    const unsigned short* __restrict__ Kr,
    const unsigned short* __restrict__ Vc,
    const float* __restrict__ x,
    const float* __restrict__ gamma,
    float* __restrict__ out,
    int* __restrict__ cnts, int* __restrict__ flags,
    float* __restrict__ Mm, float* __restrict__ Ll)
{
    const int C = 256, N = 4096;
    __shared__ __align__(16) unsigned short KV[16384];      // 32 KB: K | V
    __shared__ float Lw[4][32];
    __shared__ int tick;

    const int tid  = threadIdx.x;
    const int wave = tid >> 6;
    const int lane = tid & 63;
    const int quad = lane >> 4;
    const int l16  = lane & 15;
    const int bid  = blockIdx.x;
    const int quarter = bid & 3;
    const int b    = (bid >> 2) & 7;
    const int qt   = bid >> 5;
    const int pid  = b * 32 + qt;
    const int q0   = qt * 128 + wave * 32;
    const int kq   = quarter * 1024;

    const unsigned short* kb  = Kr + (size_t)b * N * C;
    const unsigned short* vcb = Vc + (size_t)b * C * N;

    // Q fragments (B-operand): one u32 per (ch, pair l16) = tokens (q0+l16, +16)
    short8 aqL[8], aqH[8];
    {
        const unsigned int* qb32 = (const unsigned int*)(Qc + (size_t)b * C * N);
#pragma unroll
        for (int f = 0; f < 8; f++) {
#pragma unroll
            for (int j = 0; j < 8; j++) {
                size_t i32 = ((size_t)(f * 32 + quad * 8 + j) * N + q0) / 2 + l16;
                unsigned int u = qb32[i32];
                aqL[f][j] = (short)(u & 0xffff);
                aqH[f][j] = (short)(u >> 16);
            }
        }
    }

    f32x4 oL[16], oH[16];
#pragma unroll
    for (int t = 0; t < 16; t++) {
        oL[t] = (f32x4){0.f, 0.f, 0.f, 0.f};
        oH[t] = (f32x4){0.f, 0.f, 0.f, 0.f};
    }
    float m_w = -__builtin_inff();
    float l_pL = 0.f, l_pH = 0.f;

    // staging (256 thr x 4 chunks of 16 B each per tile)
    auto stageK = [&](int it) {
#pragma unroll
        for (int p = 0; p < 4; p++) {
            int chunk = p * 256 + tid;                  // 0..1023
            int key = chunk >> 5;
            int j = (chunk & 31) ^ (key & 31);
            load_lds16(kb + (size_t)(kq + it * 32 + key) * C + j * 8,
                       &KV[chunk * 8]);
        }
    };
    auto stageV = [&](int it) {
#pragma unroll
        for (int p = 0; p < 4; p++) {
            int chunk = p * 256 + tid;                  // 0..1023
            int c = chunk >> 2;
            int s = chunk & 3;
            int j = (s - (c >> 1)) & 3;                 // source pre-rotation
            load_lds16(vcb + (size_t)c * N + kq + it * 32 + j * 8,
                       &KV[8192 + chunk * 8]);
        }
    };

    f32x4 tL0, tL1, tH0, tH1;
    auto qk = [&]() {
        const unsigned short* Kb = &KV[0];
        f32x4 a0 = {0.f,0.f,0.f,0.f}, a1 = {0.f,0.f,0.f,0.f};
        f32x4 b0 = {0.f,0.f,0.f,0.f}, b1 = {0.f,0.f,0.f,0.f};
#pragma unroll
        for (int f = 0; f < 8; f++) {
            const int j = f * 4 + quad;
            int k0 = l16, k1 = 16 + l16;
            short8 kf0 = *(const short8*)(Kb + (k0 * 32 + (j ^ (k0 & 31))) * 8);
            short8 kf1 = *(const short8*)(Kb + (k1 * 32 + (j ^ (k1 & 31))) * 8);
            a0 = MFMA16(kf0, aqL[f], a0);
            a1 = MFMA16(kf1, aqL[f], a1);
            b0 = MFMA16(kf0, aqH[f], b0);
            b1 = MFMA16(kf1, aqH[f], b1);
        }
        tL0 = a0; tL1 = a1; tH0 = b0; tH1 = b1;
    };

    const int vsl = ((quad + (l16 >> 1)) & 3) * 8;

    stageK(0);
    stageV(0);
    __syncthreads();            // tile 0 landed

    for (int it = 0; it < 32; ++it) {
        qk();                           // reads K(it)
        __syncthreads();                // K reads done; stageV(it) landed
        if (it < 31) stageK(it + 1);    // lands by next barrier

        // ---- softmax(it)
        float mx = fmaxf(fmaxf(fmaxf(tL0[0], tL0[1]), fmaxf(tL0[2], tL0[3])),
                         fmaxf(fmaxf(tL1[0], tL1[1]), fmaxf(tL1[2], tL1[3])));
        mx = fmaxf(mx, fmaxf(fmaxf(fmaxf(tH0[0], tH0[1]), fmaxf(tH0[2], tH0[3])),
                             fmaxf(fmaxf(tH1[0], tH1[1]), fmaxf(tH1[2], tH1[3]))));
        mx = rowmax16_dpp(mx);
        mx = wavemax_bcast(mx);
        if (mx > m_w + 8.0f) {
            const float al = exp2f(m_w - mx);
            m_w = mx;
            l_pL *= al; l_pH *= al;
#pragma unroll
            for (int t = 0; t < 16; t++) { oL[t] *= al; oH[t] *= al; }
        }
        const float mn = m_w;

        uint4v apLu, apHu;
#pragma unroll
        for (int w = 0; w < 4; w++) {
            float e0 = exp2f(tL0[w] - mn);
            float e1 = exp2f(tL1[w] - mn);
            l_pL += e0 + e1;
            union { __hip_bfloat162 v; unsigned int u; } cv;
            cv.v = __float22bfloat162_rn(float2{e0, e1});
            apLu[w] = cv.u;
            float g0 = exp2f(tH0[w] - mn);
            float g1 = exp2f(tH1[w] - mn);
            l_pH += g0 + g1;
            union { __hip_bfloat162 v; unsigned int u; } cw;
            cw.v = __float22bfloat162_rn(float2{g0, g1});
            apHu[w] = cw.u;
        }
        short8 apL, apH;
        {
            union { uint4v u; short8 s; } c1; c1.u = apLu; apL = c1.s;
            union { uint4v u; short8 s; } c2; c2.u = apHu; apH = c2.s;
        }

        // ---- PV(it): reads V(it)
        {
            const unsigned short* Vb = &KV[8192];
#pragma unroll
            for (int t = 0; t < 16; t++) {
                short8 vf = *(const short8*)(Vb + t * 512 + l16 * 32 + vsl);
                oL[t] = MFMA16(apL, vf, oL[t]);
                oH[t] = MFMA16(apH, vf, oH[t]);
            }
        }
        __syncthreads();                // V reads done; stageK(it+1) landed
        if (it < 31) stageV(it + 1);    // lands by next barrier
    }

    // ---- l reduce over quads: all lanes end with l for q=l16 (L) / 16+l16 (H)
    l_pL += __shfl_xor(l_pL, 16);
    l_pL += __shfl_xor(l_pL, 32);
    l_pH += __shfl_xor(l_pH, 16);
    l_pH += __shfl_xor(l_pH, 32);

    // ---- ticket-chain merge of the 4 quarter-blocks -------------------------
    __syncthreads();
    if (tid == 0) tick = atomicAdd(&cnts[pid], 1);
    __syncthreads();
    const int t = tick;

    if (t > 0) {
        if (tid == 0) {
            while (atomicAdd(&flags[pid], 0) != t) __builtin_amdgcn_s_sleep(8);
        }
        __syncthreads();
        __threadfence();                // invalidate before reading partner data
    }

    float f1, f2, mt;
    float l1L = 0.f, l1H = 0.f;
    if (t > 0) {
        const float m1 = Mm[pid * 4 + wave];
        mt = fmaxf(m1, m_w);
        f1 = exp2f(m1 - mt);
        f2 = exp2f(m_w - mt);
        l1L = Ll[pid * 128 + wave * 32 + l16];
        l1H = Ll[pid * 128 + wave * 32 + 16 + l16];
    } else {
        mt = m_w; f1 = 0.f; f2 = 1.f;
    }
    const float lnL = l1L * f1 + l_pL * f2;
    const float lnH = l1H * f1 + l_pH * f2;

    if (t < 3) {
        if (quad == 0) {
            Ll[pid * 128 + wave * 32 + l16] = lnL;
            Ll[pid * 128 + wave * 32 + 16 + l16] = lnH;
        }
        if (lane == 0) Mm[pid * 4 + wave] = mt;
        // O partial: out <- own (t==0) or merged (t==1,2), unnormalized f32
#pragma unroll
        for (int ti = 0; ti < 16; ti++) {
            const int c = ti * 16 + l16;
#pragma unroll
            for (int h = 0; h < 2; h++) {
                const int nb = q0 + h * 16 + quad * 4;
                f32x4 own = h ? oH[ti] : oL[ti];
                size_t idx = ((size_t)(b * C + c)) * N + nb;
                f32x4 ov;
                if (t == 0) {
                    ov = own;
                } else {
                    f32x4 prev = *(const f32x4*)(out + idx);
#pragma unroll
                    for (int r = 0; r < 4; r++) ov[r] = prev[r] * f1 + own[r] * f2;
                }
                *(f32x4*)(out + idx) = ov;
            }
        }
        __syncthreads();
        if (tid == 0) {
            __threadfence();            // partials visible before release
            atomicExch(&flags[pid], t + 1);
        }
    } else {
        // final: merge + normalize + gamma + residual
        if (quad == 0) {                // redistribute merged l via wave-local LDS
            Lw[wave][l16] = lnL;
            Lw[wave][16 + l16] = lnH;
        }
        const float g = gamma[0];
        float linv[2][4];
#pragma unroll
        for (int h = 0; h < 2; h++)
#pragma unroll
            for (int r = 0; r < 4; r++)
                linv[h][r] = g / Lw[wave][h * 16 + quad * 4 + r];
#pragma unroll
        for (int ti = 0; ti < 16; ti++) {
            const int c = ti * 16 + l16;
#pragma unroll
            for (int h = 0; h < 2; h++) {
                const int nb = q0 + h * 16 + quad * 4;
                f32x4 own = h ? oH[ti] : oL[ti];
                size_t idx = ((size_t)(b * C + c)) * N + nb;
                f32x4 prev = *(const f32x4*)(out + idx);
                f32x4 xv = *(const f32x4*)(x + idx);
                f32x4 ov;
#pragma unroll
                for (int r = 0; r < 4; r++)
                    ov[r] = (prev[r] * f1 + own[r] * f2) * linv[h][r] + xv[r];
                *(f32x4*)(out + idx) = ov;
            }
        }
    }
}

extern "C" void kernel_launch(void* const* d_in, const int* in_sizes, int n_in,
                              void* d_out, int out_size, void* d_ws, size_t ws_size,
                              hipStream_t stream) {
    const int B = 8, C = 256, N = 4096;
    const float* x     = (const float*)d_in[0];
    const float* wq    = (const float*)d_in[1];
    const float* bq    = (const float*)d_in[2];
    const float* wk    = (const float*)d_in[3];
    const float* bk    = (const float*)d_in[4];
    const float* wv    = (const float*)d_in[5];
    const float* bv    = (const float*)d_in[6];
    const float* gamma = (const float*)d_in[7];
    float* out = (float*)d_out;

    unsigned short* Qc = (unsigned short*)d_ws;             // [B][C][N] bf16 (x log2e), pair-interleaved
    unsigned short* Kr = Qc + (size_t)B * C * N;            // [B][N][C] bf16
    unsigned short* Vc = Kr + (size_t)B * N * C;            // [B][C][N] bf16, pair-interleaved
    unsigned short* Wb = Vc + (size_t)B * C * N;            // [3][256][256] bf16
    int*   cnts  = (int*)(Wb + 196608);                     // [256]
    int*   flags = cnts + 256;                              // [256]
    float* Mm    = (float*)(flags + 256);                   // [256][4]
    float* Ll    = Mm + 1024;                               // [256][128]

    wcvt_kernel<<<dim3(192), 256, 0, stream>>>(wq, wk, wv, Wb, cnts);
    qkv_kernel<<<dim3(1024), 256, 0, stream>>>(x, Wb, bq, bk, bv, Qc, Kr, Vc);
    attn_kernel<<<dim3(1024), 256, 0, stream>>>(Qc, Kr, Vc, x, gamma, out,
                                                cnts, flags, Mm, Ll);
}

// Round 10
// 400.413 us; speedup vs baseline: 5.3109x; 5.3109x over previous
//
#include <hip/hip_runtime.h>
#include <hip/hip_bf16.h>
#include <cstdint>

// B=8, C=256, N=4096 spatial self-attention.
// R14 = R10's per-wave structure with the in-block key-split replaced by a
// cross-block split: 512 blocks (qt, b, half) x 256 thr (4 waves x 32 q),
// 64 KB LDS (double-buffered K16|V16) -> 2 independent blocks/CU. Same
// 8 waves/CU as R10 but TWO barrier domains that drift out of phase, so one
// block's softmax overlaps the other's LDS/MFMA bursts (R12 failed because
// its groups shared one barrier; R8 failed because its grid gave 1 block/CU).
// Halves merge via 2-ticket chain through `out` (R13-proven): t=0 stores
// unnormalized O + m/l, fence, flag; t=1 spins ~skew, rescale-merges,
// normalizes + gamma + residual. Occupancy lesson (R11/R13): >2 waves/SIMD
// is impossible at ~250 regs/wave state -> this is a stall-overlap play.
// Keeps: V-read rotation (0 conflicts), swapped QK^T w/ lane-local P, DPP
// wave-max, defer-rescale THR=8, Q/V pair-interleave, XOR K staging, 3-pass qkv.

typedef short short8 __attribute__((ext_vector_type(8)));
typedef short short4v __attribute__((ext_vector_type(4)));
typedef float f32x4 __attribute__((ext_vector_type(4)));
typedef unsigned int uint4v __attribute__((ext_vector_type(4)));

#define MFMA16(a, b, c) __builtin_amdgcn_mfma_f32_16x16x32_bf16((a), (b), (c), 0, 0, 0)
#define LOG2E 1.4426950408889634f

__device__ __forceinline__ unsigned short f2bf(float f) {
    union { float f; unsigned int u; } v;
    v.f = f;
    unsigned int u = v.u;
    return (unsigned short)((u + 0x7fffu + ((u >> 16) & 1u)) >> 16);
}

__device__ __forceinline__ void load_lds16(const unsigned short* g, unsigned short* l) {
    __builtin_amdgcn_global_load_lds(
        (const __attribute__((address_space(1))) unsigned int*)g,
        (__attribute__((address_space(3))) unsigned int*)l, 16, 0, 0);
}

// max over the 16-lane row group via DPP row_ror (VALU only, no LDS unit)
__device__ __forceinline__ float rowmax16_dpp(float x) {
    int v;
    v = __builtin_amdgcn_update_dpp(0, __float_as_int(x), 0x121, 0xf, 0xf, false);
    x = fmaxf(x, __int_as_float(v));
    v = __builtin_amdgcn_update_dpp(0, __float_as_int(x), 0x122, 0xf, 0xf, false);
    x = fmaxf(x, __int_as_float(v));
    v = __builtin_amdgcn_update_dpp(0, __float_as_int(x), 0x124, 0xf, 0xf, false);
    x = fmaxf(x, __int_as_float(v));
    v = __builtin_amdgcn_update_dpp(0, __float_as_int(x), 0x128, 0xf, 0xf, false);
    x = fmaxf(x, __int_as_float(v));
    return x;
}

// 16-group maxes -> full-wave max broadcast, VALU-only (row_bcast15/31 + readlane)
__device__ __forceinline__ float wavemax_bcast(float x) {
    int v;
    v = __builtin_amdgcn_update_dpp(__float_as_int(x), __float_as_int(x), 0x142, 0xf, 0xf, false);
    x = fmaxf(x, __int_as_float(v));
    v = __builtin_amdgcn_update_dpp(__float_as_int(x), __float_as_int(x), 0x143, 0xf, 0xf, false);
    x = fmaxf(x, __int_as_float(v));
    return __int_as_float(__builtin_amdgcn_readlane(__float_as_int(x), 63));
}

// ---------------- Kernel 0: weight fp32 -> bf16 + meta zero ------------------
__global__ __launch_bounds__(256) void wcvt_kernel(
    const float* __restrict__ wq, const float* __restrict__ wk,
    const float* __restrict__ wv, unsigned short* __restrict__ Wb,
    int* __restrict__ meta)     // [cnts[256] | flags[256]]
{
    if (blockIdx.x == 0 && threadIdx.x < 256) {
        meta[threadIdx.x] = 0;
        meta[256 + threadIdx.x] = 0;
    }
    int idx = (blockIdx.x * 256 + threadIdx.x) * 4;
    const float* src = (idx < 65536) ? wq : ((idx < 131072) ? wk : wv);
    float4 f = *(const float4*)(src + (idx & 65535));
    short4v s = { (short)f2bf(f.x), (short)f2bf(f.y), (short)f2bf(f.z), (short)f2bf(f.w) };
    *(short4v*)(Wb + idx) = s;
}

// ---------------- Kernel 1: QKV projection via MFMA --------------------------
// 1024 blocks x 256 thr (4 waves). Block: batch b, 32 tokens; wave: 64 channels.
// Three sequential passes (Q, V, K). Qc AND Vc both [B][C][N] bf16,
// pair-interleaved per 32-token chunk: u32 slot a <- tokens (a, a+16).
// Q pre-scaled by log2e. Kr [B][N][C].
__global__ __launch_bounds__(256, 2) void qkv_kernel(
    const float* __restrict__ x, const unsigned short* __restrict__ Wb,
    const float* __restrict__ bq, const float* __restrict__ bk,
    const float* __restrict__ bv,
    unsigned short* __restrict__ Qc, unsigned short* __restrict__ Kr,
    unsigned short* __restrict__ Vc)
{
    const int C = 256, N = 4096;
    __shared__ __align__(16) unsigned short Xt[32][264];   // [token][c], pad 264

    const int tid  = threadIdx.x;
    const int bid  = blockIdx.x;
    const int b    = bid >> 7;
    const int n0   = (bid & 127) * 32;
    const int wave = tid >> 6;
    const int lane = tid & 63;
    const int quad = lane >> 4;
    const int l16  = lane & 15;
    const int ch0  = wave * 64;

    // stage X^T tile: fp32 [c][token] -> bf16 LDS [token][c]
    {
        const int token = tid & 31;
        const int cg    = tid >> 5;
        const float* xb = x + ((size_t)b * C) * N + n0 + token;
#pragma unroll
        for (int p = 0; p < 8; p++) {
            int c0 = p * 32 + cg * 4;
            float f0 = xb[(size_t)(c0 + 0) * N];
            float f1 = xb[(size_t)(c0 + 1) * N];
            float f2 = xb[(size_t)(c0 + 2) * N];
            float f3 = xb[(size_t)(c0 + 3) * N];
            short4v s = { (short)f2bf(f0), (short)f2bf(f1), (short)f2bf(f2), (short)f2bf(f3) };
            *(short4v*)(&Xt[token][c0]) = s;
        }
    }
    __syncthreads();

    f32x4 acc[4][2];

    // ---------------- pass 0: Q (m=0), scaled by log2e, pair-interleaved -----
#pragma unroll
    for (int ct = 0; ct < 4; ct++)
#pragma unroll
        for (int tt = 0; tt < 2; tt++) acc[ct][tt] = (f32x4){0.f, 0.f, 0.f, 0.f};
#pragma unroll
    for (int kc = 0; kc < 8; kc++) {
        const int ko = kc * 32 + quad * 8;
        short8 ax0 = *(const short8*)(&Xt[l16][ko]);
        short8 ax1 = *(const short8*)(&Xt[16 + l16][ko]);
#pragma unroll
        for (int ct = 0; ct < 4; ct++) {
            short8 wf = *(const short8*)(Wb + (ch0 + ct * 16 + l16) * 256 + ko);
            acc[ct][0] = MFMA16(ax0, wf, acc[ct][0]);
            acc[ct][1] = MFMA16(ax1, wf, acc[ct][1]);
        }
    }
#pragma unroll
    for (int ct = 0; ct < 4; ct++) {
        const int ch = ch0 + ct * 16 + l16;
        const float biq = bq[ch];
        uint4v qv;
#pragma unroll
        for (int r = 0; r < 4; r++) {
            unsigned int lo = f2bf((acc[ct][0][r] + biq) * LOG2E);   // token quad*4+r
            unsigned int hi = f2bf((acc[ct][1][r] + biq) * LOG2E);   // token quad*4+r+16
            qv[r] = lo | (hi << 16);
        }
        *(uint4v*)(Qc + ((size_t)b * C + ch) * N + n0 + quad * 8) = qv;
    }

    // ---------------- pass 1: V (m=2), pair-interleaved b128 stores ----------
#pragma unroll
    for (int ct = 0; ct < 4; ct++)
#pragma unroll
        for (int tt = 0; tt < 2; tt++) acc[ct][tt] = (f32x4){0.f, 0.f, 0.f, 0.f};
#pragma unroll
    for (int kc = 0; kc < 8; kc++) {
        const int ko = kc * 32 + quad * 8;
        short8 ax0 = *(const short8*)(&Xt[l16][ko]);
        short8 ax1 = *(const short8*)(&Xt[16 + l16][ko]);
#pragma unroll
        for (int ct = 0; ct < 4; ct++) {
            short8 wf = *(const short8*)(Wb + (2 << 16) + (ch0 + ct * 16 + l16) * 256 + ko);
            acc[ct][0] = MFMA16(ax0, wf, acc[ct][0]);
            acc[ct][1] = MFMA16(ax1, wf, acc[ct][1]);
        }
    }
#pragma unroll
    for (int ct = 0; ct < 4; ct++) {
        const int ch = ch0 + ct * 16 + l16;
        const float biv = bv[ch];
        uint4v vv;
#pragma unroll
        for (int r = 0; r < 4; r++) {
            unsigned int lo = f2bf(acc[ct][0][r] + biv);
            unsigned int hi = f2bf(acc[ct][1][r] + biv);
            vv[r] = lo | (hi << 16);
        }
        *(uint4v*)(Vc + ((size_t)b * C + ch) * N + n0 + quad * 8) = vv;
    }

    // ---------------- pass 2: K (m=1), transpose via LDS ----------------
#pragma unroll
    for (int ct = 0; ct < 4; ct++)
#pragma unroll
        for (int tt = 0; tt < 2; tt++) acc[ct][tt] = (f32x4){0.f, 0.f, 0.f, 0.f};
#pragma unroll
    for (int kc = 0; kc < 8; kc++) {
        const int ko = kc * 32 + quad * 8;
        short8 ax0 = *(const short8*)(&Xt[l16][ko]);
        short8 ax1 = *(const short8*)(&Xt[16 + l16][ko]);
#pragma unroll
        for (int ct = 0; ct < 4; ct++) {
            short8 wf = *(const short8*)(Wb + (1 << 16) + (ch0 + ct * 16 + l16) * 256 + ko);
            acc[ct][0] = MFMA16(ax0, wf, acc[ct][0]);
            acc[ct][1] = MFMA16(ax1, wf, acc[ct][1]);
        }
    }
    __syncthreads();    // Xt reads all done (all passes)
#pragma unroll
    for (int ct = 0; ct < 4; ct++) {
        const int ch = ch0 + ct * 16 + l16;
        const float bik = bk[ch];
#pragma unroll
        for (int tt = 0; tt < 2; tt++) {
#pragma unroll
            for (int r = 0; r < 4; r++)
                Xt[tt * 16 + quad * 4 + r][ch] = f2bf(acc[ct][tt][r] + bik);
        }
    }
    __syncthreads();
#pragma unroll
    for (int p = 0; p < 2; p++) {
        int chunk = p * 256 + tid;          // 0..511
        int tok = chunk >> 4;
        int cc  = (chunk & 15) * 16;
        *(short8*)(Kr + ((size_t)b * N + n0 + tok) * C + cc) = *(const short8*)(&Xt[tok][cc]);
    }
}

// ---------------- Kernel 2: flash attention (half-blocks) --------------------
// 512 blocks x 256 thr (4 waves): half = bid&1, b = (bid>>1)&7, qt = bid>>4.
// Wave w: queries q0 = qt*128 + w*32, keys [half*2048, +2048), 64 iters KT=32,
// double-buffered 64 KB LDS -> 2 independent blocks/CU (decoupled barriers).
// Loop = R10 cadence: softmax(it); PV(it); bar; stage(it+2); qk(it+1).
// 2-ticket merge via out: t=0 stores unnormalized O + m/l; t=1 merges+final.
__global__ __launch_bounds__(256, 2) void attn_kernel(
    const unsigned short* __restrict__ Qc,
    const unsigned short* __restrict__ Kr,
    const unsigned short* __restrict__ Vc,
    const float* __restrict__ x,
    const float* __restrict__ gamma,
    float* __restrict__ out,
    int* __restrict__ cnts, int* __restrict__ flags,
    float* __restrict__ Mm, float* __restrict__ Ll)
{
    const int C = 256, N = 4096;
    __shared__ __align__(16) unsigned short KV[2][16384];   // 64 KB: 2 x (K|V)
    __shared__ float Lw[4][32];
    __shared__ int tick;

    const int tid  = threadIdx.x;
    const int wave = tid >> 6;
    const int lane = tid & 63;
    const int quad = lane >> 4;
    const int l16  = lane & 15;
    const int bid  = blockIdx.x;
    const int half = bid & 1;
    const int b    = (bid >> 1) & 7;
    const int qt   = bid >> 4;
    const int pid  = b * 32 + qt;
    const int q0   = qt * 128 + wave * 32;
    const int kh   = half * 2048;

    const unsigned short* kb  = Kr + (size_t)b * N * C;
    const unsigned short* vcb = Vc + (size_t)b * C * N;

    // Q fragments (B-operand): one u32 per (ch, pair l16) = tokens (q0+l16, +16)
    short8 aqL[8], aqH[8];
    {
        const unsigned int* qb32 = (const unsigned int*)(Qc + (size_t)b * C * N);
#pragma unroll
        for (int f = 0; f < 8; f++) {
#pragma unroll
            for (int j = 0; j < 8; j++) {
                size_t i32 = ((size_t)(f * 32 + quad * 8 + j) * N + q0) / 2 + l16;
                unsigned int u = qb32[i32];
                aqL[f][j] = (short)(u & 0xffff);
                aqH[f][j] = (short)(u >> 16);
            }
        }
    }

    f32x4 oL[16], oH[16];
#pragma unroll
    for (int t = 0; t < 16; t++) {
        oL[t] = (f32x4){0.f, 0.f, 0.f, 0.f};
        oH[t] = (f32x4){0.f, 0.f, 0.f, 0.f};
    }
    float m_w = -__builtin_inff();
    float l_pL = 0.f, l_pH = 0.f;

    // stage one KT=32 K/V tile into KV[buf] (256 thr x 8 chunks of 16 B)
    auto stage = [&](int buf, int m0) {
        unsigned short* dst = &KV[buf][0];
#pragma unroll
        for (int p = 0; p < 4; p++) {               // K: 1024 chunks
            int chunk = p * 256 + tid;
            int key = chunk >> 5;
            int j = (chunk & 31) ^ (key & 31);
            load_lds16(kb + (size_t)(kh + m0 + key) * C + j * 8, dst + chunk * 8);
        }
#pragma unroll
        for (int p = 0; p < 4; p++) {               // V: 1024 chunks
            int chunk = p * 256 + tid;
            int c = chunk >> 2;
            int s = chunk & 3;
            int j = (s - (c >> 1)) & 3;             // source pre-rotation
            load_lds16(vcb + (size_t)c * N + kh + m0 + j * 8,
                       dst + 8192 + chunk * 8);
        }
    };

    // S^T tile registers (persist across the pipeline boundary)
    f32x4 tL0, tL1, tH0, tH1;

    auto qk = [&](int buf) {
        const unsigned short* Kb = &KV[buf][0];
        f32x4 a0 = {0.f,0.f,0.f,0.f}, a1 = {0.f,0.f,0.f,0.f};
        f32x4 b0 = {0.f,0.f,0.f,0.f}, b1 = {0.f,0.f,0.f,0.f};
#pragma unroll
        for (int f = 0; f < 8; f++) {
            const int j = f * 4 + quad;
            int k0 = l16, k1 = 16 + l16;
            short8 kf0 = *(const short8*)(Kb + (k0 * 32 + (j ^ (k0 & 31))) * 8);
            short8 kf1 = *(const short8*)(Kb + (k1 * 32 + (j ^ (k1 & 31))) * 8);
            a0 = MFMA16(kf0, aqL[f], a0);
            a1 = MFMA16(kf1, aqL[f], a1);
            b0 = MFMA16(kf0, aqH[f], b0);
            b1 = MFMA16(kf1, aqH[f], b1);
        }
        tL0 = a0; tL1 = a1; tH0 = b0; tH1 = b1;
    };

    const int vsl = ((quad + (l16 >> 1)) & 3) * 8;  // V read slot (lane-const)

    stage(0, 0);
    __syncthreads();            // stage(0) landed
    stage(1, 32);               // in flight through qk(0)+softmax(0)+PV(0)
    qk(0);

    for (int it = 0; it < 64; ++it) {
        // ---- softmax(it)
        float mx = fmaxf(fmaxf(fmaxf(tL0[0], tL0[1]), fmaxf(tL0[2], tL0[3])),
                         fmaxf(fmaxf(tL1[0], tL1[1]), fmaxf(tL1[2], tL1[3])));
        mx = fmaxf(mx, fmaxf(fmaxf(fmaxf(tH0[0], tH0[1]), fmaxf(tH0[2], tH0[3])),
                             fmaxf(fmaxf(tH1[0], tH1[1]), fmaxf(tH1[2], tH1[3]))));
        mx = rowmax16_dpp(mx);
        mx = wavemax_bcast(mx);

        if (mx > m_w + 8.0f) {          // defer-rescale (T13)
            const float al = exp2f(m_w - mx);
            m_w = mx;
            l_pL *= al; l_pH *= al;
#pragma unroll
            for (int t = 0; t < 16; t++) { oL[t] *= al; oH[t] *= al; }
        }
        const float mn = m_w;

        uint4v apLu, apHu;
#pragma unroll
        for (int w = 0; w < 4; w++) {
            float e0 = exp2f(tL0[w] - mn);
            float e1 = exp2f(tL1[w] - mn);
            l_pL += e0 + e1;
            union { __hip_bfloat162 v; unsigned int u; } cv;
            cv.v = __float22bfloat162_rn(float2{e0, e1});
            apLu[w] = cv.u;
            float g0 = exp2f(tH0[w] - mn);
            float g1 = exp2f(tH1[w] - mn);
            l_pH += g0 + g1;
            union { __hip_bfloat162 v; unsigned int u; } cw;
            cw.v = __float22bfloat162_rn(float2{g0, g1});
            apHu[w] = cw.u;
        }
        short8 apL, apH;
        {
            union { uint4v u; short8 s; } c1; c1.u = apLu; apL = c1.s;
            union { uint4v u; short8 s; } c2; c2.u = apHu; apH = c2.s;
        }

        // ---- PV(it): 16 channel-tiles from KV[it&1] (staged long ago)
        {
            const unsigned short* Vb = &KV[it & 1][8192];
#pragma unroll
            for (int t = 0; t < 16; t++) {
                short8 vf = *(const short8*)(Vb + t * 512 + l16 * 32 + vsl);
                oL[t] = MFMA16(apL, vf, oL[t]);
                oH[t] = MFMA16(apH, vf, oH[t]);
            }
        }

        // ---- single barrier: stage(it+1) landed; KV[it&1] reads done
        if (it < 63) {
            __syncthreads();
            if (it < 62) stage(it & 1, (it + 2) * 32);
            qk((it + 1) & 1);
        }
    }

    // ---- l reduce over quads: all lanes end with l(q=l16) / l(q=16+l16)
    l_pL += __shfl_xor(l_pL, 16);
    l_pL += __shfl_xor(l_pL, 32);
    l_pH += __shfl_xor(l_pH, 16);
    l_pH += __shfl_xor(l_pH, 32);

    // ---- 2-ticket merge of the two half-blocks ------------------------------
    __syncthreads();
    if (tid == 0) tick = atomicAdd(&cnts[pid], 1);
    __syncthreads();
    const int t = tick;

    if (t == 0) {
        // store partial m, l, and unnormalized O
        if (quad == 0) {
            Ll[pid * 128 + wave * 32 + l16] = l_pL;
            Ll[pid * 128 + wave * 32 + 16 + l16] = l_pH;
        }
        if (lane == 0) Mm[pid * 4 + wave] = m_w;
#pragma unroll
        for (int ti = 0; ti < 16; ti++) {
            const int c = ti * 16 + l16;
#pragma unroll
            for (int h = 0; h < 2; h++) {
                const int nb = q0 + h * 16 + quad * 4;
                f32x4 own = h ? oH[ti] : oL[ti];
                size_t idx = ((size_t)(b * C + c)) * N + nb;
                *(f32x4*)(out + idx) = own;
            }
        }
        __syncthreads();
        if (tid == 0) {
            __threadfence();            // partials visible before release
            atomicExch(&flags[pid], 1);
        }
    } else {
        if (tid == 0) {
            while (atomicAdd(&flags[pid], 0) != 1) __builtin_amdgcn_s_sleep(8);
        }
        __syncthreads();
        __threadfence();                // acquire partner's data

        const float m1 = Mm[pid * 4 + wave];
        const float mt = fmaxf(m1, m_w);
        const float f1 = exp2f(m1 - mt);
        const float f2 = exp2f(m_w - mt);
        const float lnL = Ll[pid * 128 + wave * 32 + l16] * f1 + l_pL * f2;
        const float lnH = Ll[pid * 128 + wave * 32 + 16 + l16] * f1 + l_pH * f2;
        if (quad == 0) {                // redistribute merged l via wave LDS
            Lw[wave][l16] = lnL;
            Lw[wave][16 + l16] = lnH;
        }
        const float g = gamma[0];
        float linv[2][4];
#pragma unroll
        for (int h = 0; h < 2; h++)
#pragma unroll
            for (int r = 0; r < 4; r++)
                linv[h][r] = g / Lw[wave][h * 16 + quad * 4 + r];
#pragma unroll
        for (int ti = 0; ti < 16; ti++) {
            const int c = ti * 16 + l16;
#pragma unroll
            for (int h = 0; h < 2; h++) {
                const int nb = q0 + h * 16 + quad * 4;
                f32x4 own = h ? oH[ti] : oL[ti];
                size_t idx = ((size_t)(b * C + c)) * N + nb;
                f32x4 prev = *(const f32x4*)(out + idx);
                f32x4 xv = *(const f32x4*)(x + idx);
                f32x4 ov;
#pragma unroll
                for (int r = 0; r < 4; r++)
                    ov[r] = (prev[r] * f1 + own[r] * f2) * linv[h][r] + xv[r];
                *(f32x4*)(out + idx) = ov;
            }
        }
    }
}

extern "C" void kernel_launch(void* const* d_in, const int* in_sizes, int n_in,
                              void* d_out, int out_size, void* d_ws, size_t ws_size,
                              hipStream_t stream) {
    const int B = 8, C = 256, N = 4096;
    const float* x     = (const float*)d_in[0];
    const float* wq    = (const float*)d_in[1];
    const float* bq    = (const float*)d_in[2];
    const float* wk    = (const float*)d_in[3];
    const float* bk    = (const float*)d_in[4];
    const float* wv    = (const float*)d_in[5];
    const float* bv    = (const float*)d_in[6];
    const float* gamma = (const float*)d_in[7];
    float* out = (float*)d_out;

    unsigned short* Qc = (unsigned short*)d_ws;             // [B][C][N] bf16 (x log2e), pair-interleaved
    unsigned short* Kr = Qc + (size_t)B * C * N;            // [B][N][C] bf16
    unsigned short* Vc = Kr + (size_t)B * N * C;            // [B][C][N] bf16, pair-interleaved
    unsigned short* Wb = Vc + (size_t)B * C * N;            // [3][256][256] bf16
    int*   cnts  = (int*)(Wb + 196608);                     // [256]
    int*   flags = cnts + 256;                              // [256]
    float* Mm    = (float*)(flags + 256);                   // [256][4]
    float* Ll    = Mm + 1024;                               // [256][128]

    wcvt_kernel<<<dim3(192), 256, 0, stream>>>(wq, wk, wv, Wb, cnts);
    qkv_kernel<<<dim3(1024), 256, 0, stream>>>(x, Wb, bq, bk, bv, Qc, Kr, Vc);
    attn_kernel<<<dim3(512), 256, 0, stream>>>(Qc, Kr, Vc, x, gamma, out,
                                               cnts, flags, Mm, Ll);
}

// Round 11
// 360.402 us; speedup vs baseline: 5.9005x; 1.1110x over previous
//
#include <hip/hip_runtime.h>
#include <hip/hip_bf16.h>
#include <cstdint>

// B=8, C=256, N=4096 spatial self-attention.
// R15: staged-bytes halving. Evidence (R7/R10/R12 all 237-257 despite schedule
// changes; R8 same bytes, fewer waves -> slower): attn tracks staged K/V bytes
// (~1 GB at ~4.4 TB/s L3->L2), not schedule. Fix: all 8 waves share ONE staged
// tile -- block = 256 queries (8 waves x 32 q, per-wave regs unchanged) x
// 2048 keys (half). Grid = 8b x 16qt x 2half = 256 blocks, 1/CU. Staging
// 32 KB/window/CU (was 64) -> 512 MB total, 2x FLOP/staged-byte. Loop = R10
// cadence byte-for-byte. Key-halves merge cross-block via R14's 2-ticket
// chain (all blocks co-resident -> deadlock-free); XCD affinity kept.
// Keeps: V-read rotation (0 conflicts), swapped QK^T w/ lane-local P, DPP
// wave-max, defer-rescale THR=8, Q/V pair-interleave, XOR K staging, 3-pass qkv.

typedef short short8 __attribute__((ext_vector_type(8)));
typedef short short4v __attribute__((ext_vector_type(4)));
typedef float f32x4 __attribute__((ext_vector_type(4)));
typedef unsigned int uint4v __attribute__((ext_vector_type(4)));

#define MFMA16(a, b, c) __builtin_amdgcn_mfma_f32_16x16x32_bf16((a), (b), (c), 0, 0, 0)
#define LOG2E 1.4426950408889634f

__device__ __forceinline__ unsigned short f2bf(float f) {
    union { float f; unsigned int u; } v;
    v.f = f;
    unsigned int u = v.u;
    return (unsigned short)((u + 0x7fffu + ((u >> 16) & 1u)) >> 16);
}

__device__ __forceinline__ void load_lds16(const unsigned short* g, unsigned short* l) {
    __builtin_amdgcn_global_load_lds(
        (const __attribute__((address_space(1))) unsigned int*)g,
        (__attribute__((address_space(3))) unsigned int*)l, 16, 0, 0);
}

// max over the 16-lane row group via DPP row_ror (VALU only, no LDS unit)
__device__ __forceinline__ float rowmax16_dpp(float x) {
    int v;
    v = __builtin_amdgcn_update_dpp(0, __float_as_int(x), 0x121, 0xf, 0xf, false);
    x = fmaxf(x, __int_as_float(v));
    v = __builtin_amdgcn_update_dpp(0, __float_as_int(x), 0x122, 0xf, 0xf, false);
    x = fmaxf(x, __int_as_float(v));
    v = __builtin_amdgcn_update_dpp(0, __float_as_int(x), 0x124, 0xf, 0xf, false);
    x = fmaxf(x, __int_as_float(v));
    v = __builtin_amdgcn_update_dpp(0, __float_as_int(x), 0x128, 0xf, 0xf, false);
    x = fmaxf(x, __int_as_float(v));
    return x;
}

// 16-group maxes -> full-wave max broadcast, VALU-only (row_bcast15/31 + readlane)
__device__ __forceinline__ float wavemax_bcast(float x) {
    int v;
    v = __builtin_amdgcn_update_dpp(__float_as_int(x), __float_as_int(x), 0x142, 0xf, 0xf, false);
    x = fmaxf(x, __int_as_float(v));
    v = __builtin_amdgcn_update_dpp(__float_as_int(x), __float_as_int(x), 0x143, 0xf, 0xf, false);
    x = fmaxf(x, __int_as_float(v));
    return __int_as_float(__builtin_amdgcn_readlane(__float_as_int(x), 63));
}

// ---------------- Kernel 0: weight fp32 -> bf16 + meta zero ------------------
__global__ __launch_bounds__(256) void wcvt_kernel(
    const float* __restrict__ wq, const float* __restrict__ wk,
    const float* __restrict__ wv, unsigned short* __restrict__ Wb,
    int* __restrict__ meta)     // [cnts[256] | flags[256]]
{
    if (blockIdx.x == 0 && threadIdx.x < 256) {
        meta[threadIdx.x] = 0;
        meta[256 + threadIdx.x] = 0;
    }
    int idx = (blockIdx.x * 256 + threadIdx.x) * 4;
    const float* src = (idx < 65536) ? wq : ((idx < 131072) ? wk : wv);
    float4 f = *(const float4*)(src + (idx & 65535));
    short4v s = { (short)f2bf(f.x), (short)f2bf(f.y), (short)f2bf(f.z), (short)f2bf(f.w) };
    *(short4v*)(Wb + idx) = s;
}

// ---------------- Kernel 1: QKV projection via MFMA --------------------------
// 1024 blocks x 256 thr (4 waves). Block: batch b, 32 tokens; wave: 64 channels.
// Three sequential passes (Q, V, K). Qc AND Vc both [B][C][N] bf16,
// pair-interleaved per 32-token chunk: u32 slot a <- tokens (a, a+16).
// Q pre-scaled by log2e. Kr [B][N][C].
__global__ __launch_bounds__(256, 2) void qkv_kernel(
    const float* __restrict__ x, const unsigned short* __restrict__ Wb,
    const float* __restrict__ bq, const float* __restrict__ bk,
    const float* __restrict__ bv,
    unsigned short* __restrict__ Qc, unsigned short* __restrict__ Kr,
    unsigned short* __restrict__ Vc)
{
    const int C = 256, N = 4096;
    __shared__ __align__(16) unsigned short Xt[32][264];   // [token][c], pad 264

    const int tid  = threadIdx.x;
    const int bid  = blockIdx.x;
    const int b    = bid >> 7;
    const int n0   = (bid & 127) * 32;
    const int wave = tid >> 6;
    const int lane = tid & 63;
    const int quad = lane >> 4;
    const int l16  = lane & 15;
    const int ch0  = wave * 64;

    // stage X^T tile: fp32 [c][token] -> bf16 LDS [token][c]
    {
        const int token = tid & 31;
        const int cg    = tid >> 5;
        const float* xb = x + ((size_t)b * C) * N + n0 + token;
#pragma unroll
        for (int p = 0; p < 8; p++) {
            int c0 = p * 32 + cg * 4;
            float f0 = xb[(size_t)(c0 + 0) * N];
            float f1 = xb[(size_t)(c0 + 1) * N];
            float f2 = xb[(size_t)(c0 + 2) * N];
            float f3 = xb[(size_t)(c0 + 3) * N];
            short4v s = { (short)f2bf(f0), (short)f2bf(f1), (short)f2bf(f2), (short)f2bf(f3) };
            *(short4v*)(&Xt[token][c0]) = s;
        }
    }
    __syncthreads();

    f32x4 acc[4][2];

    // ---------------- pass 0: Q (m=0), scaled by log2e, pair-interleaved -----
#pragma unroll
    for (int ct = 0; ct < 4; ct++)
#pragma unroll
        for (int tt = 0; tt < 2; tt++) acc[ct][tt] = (f32x4){0.f, 0.f, 0.f, 0.f};
#pragma unroll
    for (int kc = 0; kc < 8; kc++) {
        const int ko = kc * 32 + quad * 8;
        short8 ax0 = *(const short8*)(&Xt[l16][ko]);
        short8 ax1 = *(const short8*)(&Xt[16 + l16][ko]);
#pragma unroll
        for (int ct = 0; ct < 4; ct++) {
            short8 wf = *(const short8*)(Wb + (ch0 + ct * 16 + l16) * 256 + ko);
            acc[ct][0] = MFMA16(ax0, wf, acc[ct][0]);
            acc[ct][1] = MFMA16(ax1, wf, acc[ct][1]);
        }
    }
#pragma unroll
    for (int ct = 0; ct < 4; ct++) {
        const int ch = ch0 + ct * 16 + l16;
        const float biq = bq[ch];
        uint4v qv;
#pragma unroll
        for (int r = 0; r < 4; r++) {
            unsigned int lo = f2bf((acc[ct][0][r] + biq) * LOG2E);   // token quad*4+r
            unsigned int hi = f2bf((acc[ct][1][r] + biq) * LOG2E);   // token quad*4+r+16
            qv[r] = lo | (hi << 16);
        }
        *(uint4v*)(Qc + ((size_t)b * C + ch) * N + n0 + quad * 8) = qv;
    }

    // ---------------- pass 1: V (m=2), pair-interleaved b128 stores ----------
#pragma unroll
    for (int ct = 0; ct < 4; ct++)
#pragma unroll
        for (int tt = 0; tt < 2; tt++) acc[ct][tt] = (f32x4){0.f, 0.f, 0.f, 0.f};
#pragma unroll
    for (int kc = 0; kc < 8; kc++) {
        const int ko = kc * 32 + quad * 8;
        short8 ax0 = *(const short8*)(&Xt[l16][ko]);
        short8 ax1 = *(const short8*)(&Xt[16 + l16][ko]);
#pragma unroll
        for (int ct = 0; ct < 4; ct++) {
            short8 wf = *(const short8*)(Wb + (2 << 16) + (ch0 + ct * 16 + l16) * 256 + ko);
            acc[ct][0] = MFMA16(ax0, wf, acc[ct][0]);
            acc[ct][1] = MFMA16(ax1, wf, acc[ct][1]);
        }
    }
#pragma unroll
    for (int ct = 0; ct < 4; ct++) {
        const int ch = ch0 + ct * 16 + l16;
        const float biv = bv[ch];
        uint4v vv;
#pragma unroll
        for (int r = 0; r < 4; r++) {
            unsigned int lo = f2bf(acc[ct][0][r] + biv);
            unsigned int hi = f2bf(acc[ct][1][r] + biv);
            vv[r] = lo | (hi << 16);
        }
        *(uint4v*)(Vc + ((size_t)b * C + ch) * N + n0 + quad * 8) = vv;
    }

    // ---------------- pass 2: K (m=1), transpose via LDS ----------------
#pragma unroll
    for (int ct = 0; ct < 4; ct++)
#pragma unroll
        for (int tt = 0; tt < 2; tt++) acc[ct][tt] = (f32x4){0.f, 0.f, 0.f, 0.f};
#pragma unroll
    for (int kc = 0; kc < 8; kc++) {
        const int ko = kc * 32 + quad * 8;
        short8 ax0 = *(const short8*)(&Xt[l16][ko]);
        short8 ax1 = *(const short8*)(&Xt[16 + l16][ko]);
#pragma unroll
        for (int ct = 0; ct < 4; ct++) {
            short8 wf = *(const short8*)(Wb + (1 << 16) + (ch0 + ct * 16 + l16) * 256 + ko);
            acc[ct][0] = MFMA16(ax0, wf, acc[ct][0]);
            acc[ct][1] = MFMA16(ax1, wf, acc[ct][1]);
        }
    }
    __syncthreads();    // Xt reads all done (all passes)
#pragma unroll
    for (int ct = 0; ct < 4; ct++) {
        const int ch = ch0 + ct * 16 + l16;
        const float bik = bk[ch];
#pragma unroll
        for (int tt = 0; tt < 2; tt++) {
#pragma unroll
            for (int r = 0; r < 4; r++)
                Xt[tt * 16 + quad * 4 + r][ch] = f2bf(acc[ct][tt][r] + bik);
        }
    }
    __syncthreads();
#pragma unroll
    for (int p = 0; p < 2; p++) {
        int chunk = p * 256 + tid;          // 0..511
        int tok = chunk >> 4;
        int cc  = (chunk & 15) * 16;
        *(short8*)(Kr + ((size_t)b * N + n0 + tok) * C + cc) = *(const short8*)(&Xt[tok][cc]);
    }
}

// ---------------- Kernel 2: flash attention (shared-tile halves) -------------
// 256 blocks x 512 thr (8 waves): b = bid&7, qt = (bid>>3)&15, half = bid>>7.
// ALL 8 waves share one staged 32-key tile; wave w owns queries
// q0 = qt*256 + w*32; keys [half*2048, +2048) in 64 iters KT=32, double-buf
// 64 KB LDS, R10 cadence: sm(it); PV(it); bar; stage(it+2); qk(it+1).
// Halves merge via 2-ticket chain through `out` (t=0 stores unnormalized
// O+m/l; t=1 spins, rescale-merges, normalizes + gamma + residual).
__global__ __launch_bounds__(512, 2) void attn_kernel(
    const unsigned short* __restrict__ Qc,
    const unsigned short* __restrict__ Kr,
    const unsigned short* __restrict__ Vc,
    const float* __restrict__ x,
    const float* __restrict__ gamma,
    float* __restrict__ out,
    int* __restrict__ cnts, int* __restrict__ flags,
    float* __restrict__ Mm, float* __restrict__ Ll)
{
    const int C = 256, N = 4096;
    __shared__ __align__(16) unsigned short KV[2][16384];   // 64 KB: 2 x (K|V)
    __shared__ float Lw[8][32];
    __shared__ int tick;

    const int tid  = threadIdx.x;
    const int wave = tid >> 6;
    const int lane = tid & 63;
    const int quad = lane >> 4;
    const int l16  = lane & 15;
    const int bid  = blockIdx.x;
    const int b    = bid & 7;
    const int qt   = (bid >> 3) & 15;
    const int half = bid >> 7;
    const int pid  = b * 16 + qt;
    const int q0   = qt * 256 + wave * 32;
    const int kh   = half * 2048;

    const unsigned short* kb  = Kr + (size_t)b * N * C;
    const unsigned short* vcb = Vc + (size_t)b * C * N;

    // Q fragments (B-operand): one u32 per (ch, pair l16) = tokens (q0+l16, +16)
    short8 aqL[8], aqH[8];
    {
        const unsigned int* qb32 = (const unsigned int*)(Qc + (size_t)b * C * N);
#pragma unroll
        for (int f = 0; f < 8; f++) {
#pragma unroll
            for (int j = 0; j < 8; j++) {
                size_t i32 = ((size_t)(f * 32 + quad * 8 + j) * N + q0) / 2 + l16;
                unsigned int u = qb32[i32];
                aqL[f][j] = (short)(u & 0xffff);
                aqH[f][j] = (short)(u >> 16);
            }
        }
    }

    f32x4 oL[16], oH[16];
#pragma unroll
    for (int t = 0; t < 16; t++) {
        oL[t] = (f32x4){0.f, 0.f, 0.f, 0.f};
        oH[t] = (f32x4){0.f, 0.f, 0.f, 0.f};
    }
    float m_w = -__builtin_inff();
    float l_pL = 0.f, l_pH = 0.f;

    // stage one KT=32 tile into KV[buf]: 2048 chunks of 16 B, 4 per thread
    auto stage = [&](int buf, int m0) {
        unsigned short* dst = &KV[buf][0];
#pragma unroll
        for (int p = 0; p < 2; p++) {               // K: 1024 chunks
            int chunk = p * 512 + tid;
            int key = chunk >> 5;
            int j = (chunk & 31) ^ (key & 31);
            load_lds16(kb + (size_t)(kh + m0 + key) * C + j * 8, dst + chunk * 8);
        }
#pragma unroll
        for (int p = 0; p < 2; p++) {               // V: 1024 chunks
            int chunk = p * 512 + tid;
            int c = chunk >> 2;
            int s = chunk & 3;
            int j = (s - (c >> 1)) & 3;             // source pre-rotation
            load_lds16(vcb + (size_t)c * N + kh + m0 + j * 8,
                       dst + 8192 + chunk * 8);
        }
    };

    // S^T tile registers (persist across the pipeline boundary)
    f32x4 tL0, tL1, tH0, tH1;

    auto qk = [&](int buf) {
        const unsigned short* Kb = &KV[buf][0];
        f32x4 a0 = {0.f,0.f,0.f,0.f}, a1 = {0.f,0.f,0.f,0.f};
        f32x4 b0 = {0.f,0.f,0.f,0.f}, b1 = {0.f,0.f,0.f,0.f};
#pragma unroll
        for (int f = 0; f < 8; f++) {
            const int j = f * 4 + quad;
            int k0 = l16, k1 = 16 + l16;
            short8 kf0 = *(const short8*)(Kb + (k0 * 32 + (j ^ (k0 & 31))) * 8);
            short8 kf1 = *(const short8*)(Kb + (k1 * 32 + (j ^ (k1 & 31))) * 8);
            a0 = MFMA16(kf0, aqL[f], a0);
            a1 = MFMA16(kf1, aqL[f], a1);
            b0 = MFMA16(kf0, aqH[f], b0);
            b1 = MFMA16(kf1, aqH[f], b1);
        }
        tL0 = a0; tL1 = a1; tH0 = b0; tH1 = b1;
    };

    const int vsl = ((quad + (l16 >> 1)) & 3) * 8;  // V read slot (lane-const)

    stage(0, 0);
    __syncthreads();            // stage(0) landed
    stage(1, 32);               // in flight through qk(0)+softmax(0)+PV(0)
    qk(0);

    for (int it = 0; it < 64; ++it) {
        // ---- softmax(it)
        float mx = fmaxf(fmaxf(fmaxf(tL0[0], tL0[1]), fmaxf(tL0[2], tL0[3])),
                         fmaxf(fmaxf(tL1[0], tL1[1]), fmaxf(tL1[2], tL1[3])));
        mx = fmaxf(mx, fmaxf(fmaxf(fmaxf(tH0[0], tH0[1]), fmaxf(tH0[2], tH0[3])),
                             fmaxf(fmaxf(tH1[0], tH1[1]), fmaxf(tH1[2], tH1[3]))));
        mx = rowmax16_dpp(mx);
        mx = wavemax_bcast(mx);

        if (mx > m_w + 8.0f) {          // defer-rescale (T13)
            const float al = exp2f(m_w - mx);
            m_w = mx;
            l_pL *= al; l_pH *= al;
#pragma unroll
            for (int t = 0; t < 16; t++) { oL[t] *= al; oH[t] *= al; }
        }
        const float mn = m_w;

        uint4v apLu, apHu;
#pragma unroll
        for (int w = 0; w < 4; w++) {
            float e0 = exp2f(tL0[w] - mn);
            float e1 = exp2f(tL1[w] - mn);
            l_pL += e0 + e1;
            union { __hip_bfloat162 v; unsigned int u; } cv;
            cv.v = __float22bfloat162_rn(float2{e0, e1});
            apLu[w] = cv.u;
            float g0 = exp2f(tH0[w] - mn);
            float g1 = exp2f(tH1[w] - mn);
            l_pH += g0 + g1;
            union { __hip_bfloat162 v; unsigned int u; } cw;
            cw.v = __float22bfloat162_rn(float2{g0, g1});
            apHu[w] = cw.u;
        }
        short8 apL, apH;
        {
            union { uint4v u; short8 s; } c1; c1.u = apLu; apL = c1.s;
            union { uint4v u; short8 s; } c2; c2.u = apHu; apH = c2.s;
        }

        // ---- PV(it): 16 channel-tiles from KV[it&1] (staged long ago)
        {
            const unsigned short* Vb = &KV[it & 1][8192];
#pragma unroll
            for (int t = 0; t < 16; t++) {
                short8 vf = *(const short8*)(Vb + t * 512 + l16 * 32 + vsl);
                oL[t] = MFMA16(apL, vf, oL[t]);
                oH[t] = MFMA16(apH, vf, oH[t]);
            }
        }

        // ---- single barrier: stage(it+1) landed; KV[it&1] reads done
        if (it < 63) {
            __syncthreads();
            if (it < 62) stage(it & 1, (it + 2) * 32);
            qk((it + 1) & 1);
        }
    }

    // ---- l reduce over quads: all lanes end with l(q=l16) / l(q=16+l16)
    l_pL += __shfl_xor(l_pL, 16);
    l_pL += __shfl_xor(l_pL, 32);
    l_pH += __shfl_xor(l_pH, 16);
    l_pH += __shfl_xor(l_pH, 32);

    // ---- 2-ticket merge of the two half-blocks ------------------------------
    __syncthreads();
    if (tid == 0) tick = atomicAdd(&cnts[pid], 1);
    __syncthreads();
    const int t = tick;

    if (t == 0) {
        // store partial m, l, and unnormalized O
        if (quad == 0) {
            Ll[pid * 256 + wave * 32 + l16] = l_pL;
            Ll[pid * 256 + wave * 32 + 16 + l16] = l_pH;
        }
        if (lane == 0) Mm[pid * 8 + wave] = m_w;
#pragma unroll
        for (int ti = 0; ti < 16; ti++) {
            const int c = ti * 16 + l16;
#pragma unroll
            for (int h = 0; h < 2; h++) {
                const int nb = q0 + h * 16 + quad * 4;
                f32x4 own = h ? oH[ti] : oL[ti];
                size_t idx = ((size_t)(b * C + c)) * N + nb;
                *(f32x4*)(out + idx) = own;
            }
        }
        __syncthreads();
        if (tid == 0) {
            __threadfence();            // partials visible before release
            atomicExch(&flags[pid], 1);
        }
    } else {
        if (tid == 0) {
            while (atomicAdd(&flags[pid], 0) != 1) __builtin_amdgcn_s_sleep(8);
        }
        __syncthreads();
        __threadfence();                // acquire partner's data

        const float m1 = Mm[pid * 8 + wave];
        const float mt = fmaxf(m1, m_w);
        const float f1 = exp2f(m1 - mt);
        const float f2 = exp2f(m_w - mt);
        const float lnL = Ll[pid * 256 + wave * 32 + l16] * f1 + l_pL * f2;
        const float lnH = Ll[pid * 256 + wave * 32 + 16 + l16] * f1 + l_pH * f2;
        if (quad == 0) {                // redistribute merged l via wave LDS
            Lw[wave][l16] = lnL;
            Lw[wave][16 + l16] = lnH;
        }
        const float g = gamma[0];
        float linv[2][4];
#pragma unroll
        for (int h = 0; h < 2; h++)
#pragma unroll
            for (int r = 0; r < 4; r++)
                linv[h][r] = g / Lw[wave][h * 16 + quad * 4 + r];
#pragma unroll
        for (int ti = 0; ti < 16; ti++) {
            const int c = ti * 16 + l16;
#pragma unroll
            for (int h = 0; h < 2; h++) {
                const int nb = q0 + h * 16 + quad * 4;
                f32x4 own = h ? oH[ti] : oL[ti];
                size_t idx = ((size_t)(b * C + c)) * N + nb;
                f32x4 prev = *(const f32x4*)(out + idx);
                f32x4 xv = *(const f32x4*)(x + idx);
                f32x4 ov;
#pragma unroll
                for (int r = 0; r < 4; r++)
                    ov[r] = (prev[r] * f1 + own[r] * f2) * linv[h][r] + xv[r];
                *(f32x4*)(out + idx) = ov;
            }
        }
    }
}

extern "C" void kernel_launch(void* const* d_in, const int* in_sizes, int n_in,
                              void* d_out, int out_size, void* d_ws, size_t ws_size,
                              hipStream_t stream) {
    const int B = 8, C = 256, N = 4096;
    const float* x     = (const float*)d_in[0];
    const float* wq    = (const float*)d_in[1];
    const float* bq    = (const float*)d_in[2];
    const float* wk    = (const float*)d_in[3];
    const float* bk    = (const float*)d_in[4];
    const float* wv    = (const float*)d_in[5];
    const float* bv    = (const float*)d_in[6];
    const float* gamma = (const float*)d_in[7];
    float* out = (float*)d_out;

    unsigned short* Qc = (unsigned short*)d_ws;             // [B][C][N] bf16 (x log2e), pair-interleaved
    unsigned short* Kr = Qc + (size_t)B * C * N;            // [B][N][C] bf16
    unsigned short* Vc = Kr + (size_t)B * N * C;            // [B][C][N] bf16, pair-interleaved
    unsigned short* Wb = Vc + (size_t)B * C * N;            // [3][256][256] bf16
    int*   cnts  = (int*)(Wb + 196608);                     // [256] (128 used)
    int*   flags = cnts + 256;                              // [256] (128 used)
    float* Mm    = (float*)(flags + 256);                   // [128][8]
    float* Ll    = Mm + 1024;                               // [128][256]

    wcvt_kernel<<<dim3(192), 256, 0, stream>>>(wq, wk, wv, Wb, cnts);
    qkv_kernel<<<dim3(1024), 256, 0, stream>>>(x, Wb, bq, bk, bv, Qc, Kr, Vc);
    attn_kernel<<<dim3(256), 512, 0, stream>>>(Qc, Kr, Vc, x, gamma, out,
                                               cnts, flags, Mm, Ll);
}

// Round 12
// 352.583 us; speedup vs baseline: 6.0314x; 1.0222x over previous
//
#include <hip/hip_runtime.h>
#include <hip/hip_bf16.h>
#include <cstdint>

// B=8, C=256, N=4096 spatial self-attention.
// R16 = R15 shell (shared tile, 8 waves x 32 q, cross-block half merge) +
// mod-4 tile ring (KV[4] x 32 KB = 128 KB) + PARITY-STAGGERED schedules:
// parity p = wave>>2 (each SIMD hosts one wave of each parity).
//   window it: stage(it+2); p1: PV(it-1); qk(it); sm(it); p0: PV(it); bar
// p1's PV MFMAs run while p0 issues K-reads and vice versa -> the block-wide
// synchronized LDS-burst / MFMA / softmax phases (the ~60% stall) interleave
// across parities. Equal per-window path lengths for both parities (R12's
// failure was unequal paths + shared barrier). Ring hazards: reads {it,it-1},
// write it+2 -> all mod-4 distances distinct; every stage drains a full
// window after issue. p1 carries ap across one barrier (+8 VGPR; 2-wave/SIMD
// budget is 256, we use ~140).
// Keeps: V-read rotation (0 conflicts), swapped QK^T w/ lane-local P, DPP
// wave-max, defer-rescale THR=8, Q/V pair-interleave, XOR K staging, 3-pass
// qkv, 2-ticket cross-block merge.

typedef short short8 __attribute__((ext_vector_type(8)));
typedef short short4v __attribute__((ext_vector_type(4)));
typedef float f32x4 __attribute__((ext_vector_type(4)));
typedef unsigned int uint4v __attribute__((ext_vector_type(4)));

#define MFMA16(a, b, c) __builtin_amdgcn_mfma_f32_16x16x32_bf16((a), (b), (c), 0, 0, 0)
#define LOG2E 1.4426950408889634f

__device__ __forceinline__ unsigned short f2bf(float f) {
    union { float f; unsigned int u; } v;
    v.f = f;
    unsigned int u = v.u;
    return (unsigned short)((u + 0x7fffu + ((u >> 16) & 1u)) >> 16);
}

__device__ __forceinline__ void load_lds16(const unsigned short* g, unsigned short* l) {
    __builtin_amdgcn_global_load_lds(
        (const __attribute__((address_space(1))) unsigned int*)g,
        (__attribute__((address_space(3))) unsigned int*)l, 16, 0, 0);
}

// max over the 16-lane row group via DPP row_ror (VALU only, no LDS unit)
__device__ __forceinline__ float rowmax16_dpp(float x) {
    int v;
    v = __builtin_amdgcn_update_dpp(0, __float_as_int(x), 0x121, 0xf, 0xf, false);
    x = fmaxf(x, __int_as_float(v));
    v = __builtin_amdgcn_update_dpp(0, __float_as_int(x), 0x122, 0xf, 0xf, false);
    x = fmaxf(x, __int_as_float(v));
    v = __builtin_amdgcn_update_dpp(0, __float_as_int(x), 0x124, 0xf, 0xf, false);
    x = fmaxf(x, __int_as_float(v));
    v = __builtin_amdgcn_update_dpp(0, __float_as_int(x), 0x128, 0xf, 0xf, false);
    x = fmaxf(x, __int_as_float(v));
    return x;
}

// 16-group maxes -> full-wave max broadcast, VALU-only (row_bcast15/31 + readlane)
__device__ __forceinline__ float wavemax_bcast(float x) {
    int v;
    v = __builtin_amdgcn_update_dpp(__float_as_int(x), __float_as_int(x), 0x142, 0xf, 0xf, false);
    x = fmaxf(x, __int_as_float(v));
    v = __builtin_amdgcn_update_dpp(__float_as_int(x), __float_as_int(x), 0x143, 0xf, 0xf, false);
    x = fmaxf(x, __int_as_float(v));
    return __int_as_float(__builtin_amdgcn_readlane(__float_as_int(x), 63));
}

// ---------------- Kernel 0: weight fp32 -> bf16 + meta zero ------------------
__global__ __launch_bounds__(256) void wcvt_kernel(
    const float* __restrict__ wq, const float* __restrict__ wk,
    const float* __restrict__ wv, unsigned short* __restrict__ Wb,
    int* __restrict__ meta)     // [cnts[256] | flags[256]]
{
    if (blockIdx.x == 0 && threadIdx.x < 256) {
        meta[threadIdx.x] = 0;
        meta[256 + threadIdx.x] = 0;
    }
    int idx = (blockIdx.x * 256 + threadIdx.x) * 4;
    const float* src = (idx < 65536) ? wq : ((idx < 131072) ? wk : wv);
    float4 f = *(const float4*)(src + (idx & 65535));
    short4v s = { (short)f2bf(f.x), (short)f2bf(f.y), (short)f2bf(f.z), (short)f2bf(f.w) };
    *(short4v*)(Wb + idx) = s;
}

// ---------------- Kernel 1: QKV projection via MFMA --------------------------
// 1024 blocks x 256 thr (4 waves). Block: batch b, 32 tokens; wave: 64 channels.
// Three sequential passes (Q, V, K). Qc AND Vc both [B][C][N] bf16,
// pair-interleaved per 32-token chunk: u32 slot a <- tokens (a, a+16).
// Q pre-scaled by log2e. Kr [B][N][C].
__global__ __launch_bounds__(256, 2) void qkv_kernel(
    const float* __restrict__ x, const unsigned short* __restrict__ Wb,
    const float* __restrict__ bq, const float* __restrict__ bk,
    const float* __restrict__ bv,
    unsigned short* __restrict__ Qc, unsigned short* __restrict__ Kr,
    unsigned short* __restrict__ Vc)
{
    const int C = 256, N = 4096;
    __shared__ __align__(16) unsigned short Xt[32][264];   // [token][c], pad 264

    const int tid  = threadIdx.x;
    const int bid  = blockIdx.x;
    const int b    = bid >> 7;
    const int n0   = (bid & 127) * 32;
    const int wave = tid >> 6;
    const int lane = tid & 63;
    const int quad = lane >> 4;
    const int l16  = lane & 15;
    const int ch0  = wave * 64;

    // stage X^T tile: fp32 [c][token] -> bf16 LDS [token][c]
    {
        const int token = tid & 31;
        const int cg    = tid >> 5;
        const float* xb = x + ((size_t)b * C) * N + n0 + token;
#pragma unroll
        for (int p = 0; p < 8; p++) {
            int c0 = p * 32 + cg * 4;
            float f0 = xb[(size_t)(c0 + 0) * N];
            float f1 = xb[(size_t)(c0 + 1) * N];
            float f2 = xb[(size_t)(c0 + 2) * N];
            float f3 = xb[(size_t)(c0 + 3) * N];
            short4v s = { (short)f2bf(f0), (short)f2bf(f1), (short)f2bf(f2), (short)f2bf(f3) };
            *(short4v*)(&Xt[token][c0]) = s;
        }
    }
    __syncthreads();

    f32x4 acc[4][2];

    // ---------------- pass 0: Q (m=0), scaled by log2e, pair-interleaved -----
#pragma unroll
    for (int ct = 0; ct < 4; ct++)
#pragma unroll
        for (int tt = 0; tt < 2; tt++) acc[ct][tt] = (f32x4){0.f, 0.f, 0.f, 0.f};
#pragma unroll
    for (int kc = 0; kc < 8; kc++) {
        const int ko = kc * 32 + quad * 8;
        short8 ax0 = *(const short8*)(&Xt[l16][ko]);
        short8 ax1 = *(const short8*)(&Xt[16 + l16][ko]);
#pragma unroll
        for (int ct = 0; ct < 4; ct++) {
            short8 wf = *(const short8*)(Wb + (ch0 + ct * 16 + l16) * 256 + ko);
            acc[ct][0] = MFMA16(ax0, wf, acc[ct][0]);
            acc[ct][1] = MFMA16(ax1, wf, acc[ct][1]);
        }
    }
#pragma unroll
    for (int ct = 0; ct < 4; ct++) {
        const int ch = ch0 + ct * 16 + l16;
        const float biq = bq[ch];
        uint4v qv;
#pragma unroll
        for (int r = 0; r < 4; r++) {
            unsigned int lo = f2bf((acc[ct][0][r] + biq) * LOG2E);   // token quad*4+r
            unsigned int hi = f2bf((acc[ct][1][r] + biq) * LOG2E);   // token quad*4+r+16
            qv[r] = lo | (hi << 16);
        }
        *(uint4v*)(Qc + ((size_t)b * C + ch) * N + n0 + quad * 8) = qv;
    }

    // ---------------- pass 1: V (m=2), pair-interleaved b128 stores ----------
#pragma unroll
    for (int ct = 0; ct < 4; ct++)
#pragma unroll
        for (int tt = 0; tt < 2; tt++) acc[ct][tt] = (f32x4){0.f, 0.f, 0.f, 0.f};
#pragma unroll
    for (int kc = 0; kc < 8; kc++) {
        const int ko = kc * 32 + quad * 8;
        short8 ax0 = *(const short8*)(&Xt[l16][ko]);
        short8 ax1 = *(const short8*)(&Xt[16 + l16][ko]);
#pragma unroll
        for (int ct = 0; ct < 4; ct++) {
            short8 wf = *(const short8*)(Wb + (2 << 16) + (ch0 + ct * 16 + l16) * 256 + ko);
            acc[ct][0] = MFMA16(ax0, wf, acc[ct][0]);
            acc[ct][1] = MFMA16(ax1, wf, acc[ct][1]);
        }
    }
#pragma unroll
    for (int ct = 0; ct < 4; ct++) {
        const int ch = ch0 + ct * 16 + l16;
        const float biv = bv[ch];
        uint4v vv;
#pragma unroll
        for (int r = 0; r < 4; r++) {
            unsigned int lo = f2bf(acc[ct][0][r] + biv);
            unsigned int hi = f2bf(acc[ct][1][r] + biv);
            vv[r] = lo | (hi << 16);
        }
        *(uint4v*)(Vc + ((size_t)b * C + ch) * N + n0 + quad * 8) = vv;
    }

    // ---------------- pass 2: K (m=1), transpose via LDS ----------------
#pragma unroll
    for (int ct = 0; ct < 4; ct++)
#pragma unroll
        for (int tt = 0; tt < 2; tt++) acc[ct][tt] = (f32x4){0.f, 0.f, 0.f, 0.f};
#pragma unroll
    for (int kc = 0; kc < 8; kc++) {
        const int ko = kc * 32 + quad * 8;
        short8 ax0 = *(const short8*)(&Xt[l16][ko]);
        short8 ax1 = *(const short8*)(&Xt[16 + l16][ko]);
#pragma unroll
        for (int ct = 0; ct < 4; ct++) {
            short8 wf = *(const short8*)(Wb + (1 << 16) + (ch0 + ct * 16 + l16) * 256 + ko);
            acc[ct][0] = MFMA16(ax0, wf, acc[ct][0]);
            acc[ct][1] = MFMA16(ax1, wf, acc[ct][1]);
        }
    }
    __syncthreads();    // Xt reads all done (all passes)
#pragma unroll
    for (int ct = 0; ct < 4; ct++) {
        const int ch = ch0 + ct * 16 + l16;
        const float bik = bk[ch];
#pragma unroll
        for (int tt = 0; tt < 2; tt++) {
#pragma unroll
            for (int r = 0; r < 4; r++)
                Xt[tt * 16 + quad * 4 + r][ch] = f2bf(acc[ct][tt][r] + bik);
        }
    }
    __syncthreads();
#pragma unroll
    for (int p = 0; p < 2; p++) {
        int chunk = p * 256 + tid;          // 0..511
        int tok = chunk >> 4;
        int cc  = (chunk & 15) * 16;
        *(short8*)(Kr + ((size_t)b * N + n0 + tok) * C + cc) = *(const short8*)(&Xt[tok][cc]);
    }
}

// ---------------- Kernel 2: flash attention (staggered parities) -------------
// 256 blocks x 512 thr (8 waves): b = bid&7, qt = (bid>>3)&15, half = bid>>7.
// All 8 waves share one staged 32-key tile; wave w owns queries
// q0 = qt*256 + w*32; keys [half*2048, +2048) in 64 windows of KT=32.
// Mod-4 ring KV[4][32 KB]; parity p = wave>>2 staggers PV by one window:
//   window it: stage(it+2); p1: PV(it-1); qk(it); sm(it); p0: PV(it); bar
// Halves merge via 2-ticket chain through `out`.
__global__ __launch_bounds__(512, 2) void attn_kernel(
    const unsigned short* __restrict__ Qc,
    const unsigned short* __restrict__ Kr,
    const unsigned short* __restrict__ Vc,
    const float* __restrict__ x,
    const float* __restrict__ gamma,
    float* __restrict__ out,
    int* __restrict__ cnts, int* __restrict__ flags,
    float* __restrict__ Mm, float* __restrict__ Ll)
{
    const int C = 256, N = 4096;
    __shared__ __align__(16) unsigned short KV[4][16384];   // 128 KB: 4 x (K|V)
    __shared__ float Lw[8][32];
    __shared__ int tick;

    const int tid  = threadIdx.x;
    const int wave = tid >> 6;
    const int par  = wave >> 2;          // parity: SIMD s hosts waves s, s+4
    const int lane = tid & 63;
    const int quad = lane >> 4;
    const int l16  = lane & 15;
    const int bid  = blockIdx.x;
    const int b    = bid & 7;
    const int qt   = (bid >> 3) & 15;
    const int half = bid >> 7;
    const int pid  = b * 16 + qt;
    const int q0   = qt * 256 + wave * 32;
    const int kh   = half * 2048;

    const unsigned short* kb  = Kr + (size_t)b * N * C;
    const unsigned short* vcb = Vc + (size_t)b * C * N;

    // Q fragments (B-operand): one u32 per (ch, pair l16) = tokens (q0+l16, +16)
    short8 aqL[8], aqH[8];
    {
        const unsigned int* qb32 = (const unsigned int*)(Qc + (size_t)b * C * N);
#pragma unroll
        for (int f = 0; f < 8; f++) {
#pragma unroll
            for (int j = 0; j < 8; j++) {
                size_t i32 = ((size_t)(f * 32 + quad * 8 + j) * N + q0) / 2 + l16;
                unsigned int u = qb32[i32];
                aqL[f][j] = (short)(u & 0xffff);
                aqH[f][j] = (short)(u >> 16);
            }
        }
    }

    f32x4 oL[16], oH[16];
#pragma unroll
    for (int t = 0; t < 16; t++) {
        oL[t] = (f32x4){0.f, 0.f, 0.f, 0.f};
        oH[t] = (f32x4){0.f, 0.f, 0.f, 0.f};
    }
    float m_w = -__builtin_inff();
    float l_pL = 0.f, l_pH = 0.f;

    // stage one KT=32 tile into KV[buf]: 2048 chunks of 16 B, 4 per thread
    auto stage = [&](int buf, int m0) {
        unsigned short* dst = &KV[buf][0];
#pragma unroll
        for (int p = 0; p < 2; p++) {               // K: 1024 chunks
            int chunk = p * 512 + tid;
            int key = chunk >> 5;
            int j = (chunk & 31) ^ (key & 31);
            load_lds16(kb + (size_t)(kh + m0 + key) * C + j * 8, dst + chunk * 8);
        }
#pragma unroll
        for (int p = 0; p < 2; p++) {               // V: 1024 chunks
            int chunk = p * 512 + tid;
            int c = chunk >> 2;
            int s = chunk & 3;
            int j = (s - (c >> 1)) & 3;             // source pre-rotation
            load_lds16(vcb + (size_t)c * N + kh + m0 + j * 8,
                       dst + 8192 + chunk * 8);
        }
    };

    // S^T tile registers
    f32x4 tL0, tL1, tH0, tH1;

    auto qk = [&](int buf) {
        const unsigned short* Kb = &KV[buf][0];
        f32x4 a0 = {0.f,0.f,0.f,0.f}, a1 = {0.f,0.f,0.f,0.f};
        f32x4 b0 = {0.f,0.f,0.f,0.f}, b1 = {0.f,0.f,0.f,0.f};
#pragma unroll
        for (int f = 0; f < 8; f++) {
            const int j = f * 4 + quad;
            int k0 = l16, k1 = 16 + l16;
            short8 kf0 = *(const short8*)(Kb + (k0 * 32 + (j ^ (k0 & 31))) * 8);
            short8 kf1 = *(const short8*)(Kb + (k1 * 32 + (j ^ (k1 & 31))) * 8);
            a0 = MFMA16(kf0, aqL[f], a0);
            a1 = MFMA16(kf1, aqL[f], a1);
            b0 = MFMA16(kf0, aqH[f], b0);
            b1 = MFMA16(kf1, aqH[f], b1);
        }
        tL0 = a0; tL1 = a1; tH0 = b0; tH1 = b1;
    };

    const int vsl = ((quad + (l16 >> 1)) & 3) * 8;  // V read slot (lane-const)

    // PV A-fragments (persist across the barrier for parity 1)
    short8 apL, apH;

    auto pv = [&](int buf) {
        const unsigned short* Vb = &KV[buf][8192];
#pragma unroll
        for (int t = 0; t < 16; t++) {
            short8 vf = *(const short8*)(Vb + t * 512 + l16 * 32 + vsl);
            oL[t] = MFMA16(apL, vf, oL[t]);
            oH[t] = MFMA16(apH, vf, oH[t]);
        }
    };

    stage(0, 0);
    stage(1, 32);
    __syncthreads();            // tiles 0 and 1 landed

    for (int it = 0; it < 64; ++it) {
        if (it < 62) stage((it + 2) & 3, (it + 2) * 32);    // full window to fly

        if (par == 1 && it > 0) pv((it - 1) & 3);           // MFMA while p0 reads K

        qk(it & 3);

        // ---- softmax(it)
        float mx = fmaxf(fmaxf(fmaxf(tL0[0], tL0[1]), fmaxf(tL0[2], tL0[3])),
                         fmaxf(fmaxf(tL1[0], tL1[1]), fmaxf(tL1[2], tL1[3])));
        mx = fmaxf(mx, fmaxf(fmaxf(fmaxf(tH0[0], tH0[1]), fmaxf(tH0[2], tH0[3])),
                             fmaxf(fmaxf(tH1[0], tH1[1]), fmaxf(tH1[2], tH1[3]))));
        mx = rowmax16_dpp(mx);
        mx = wavemax_bcast(mx);

        if (mx > m_w + 8.0f) {          // defer-rescale (T13)
            const float al = exp2f(m_w - mx);
            m_w = mx;
            l_pL *= al; l_pH *= al;
#pragma unroll
            for (int t = 0; t < 16; t++) { oL[t] *= al; oH[t] *= al; }
        }
        const float mn = m_w;

        uint4v apLu, apHu;
#pragma unroll
        for (int w = 0; w < 4; w++) {
            float e0 = exp2f(tL0[w] - mn);
            float e1 = exp2f(tL1[w] - mn);
            l_pL += e0 + e1;
            union { __hip_bfloat162 v; unsigned int u; } cv;
            cv.v = __float22bfloat162_rn(float2{e0, e1});
            apLu[w] = cv.u;
            float g0 = exp2f(tH0[w] - mn);
            float g1 = exp2f(tH1[w] - mn);
            l_pH += g0 + g1;
            union { __hip_bfloat162 v; unsigned int u; } cw;
            cw.v = __float22bfloat162_rn(float2{g0, g1});
            apHu[w] = cw.u;
        }
        {
            union { uint4v u; short8 s; } c1; c1.u = apLu; apL = c1.s;
            union { uint4v u; short8 s; } c2; c2.u = apHu; apH = c2.s;
        }

        if (par == 0) pv(it & 3);       // MFMA while p1 heads into next K-reads

        __syncthreads();
    }
    if (par == 1) pv(63 & 3);           // tail: deferred last PV

    // ---- l reduce over quads: all lanes end with l(q=l16) / l(q=16+l16)
    l_pL += __shfl_xor(l_pL, 16);
    l_pL += __shfl_xor(l_pL, 32);
    l_pH += __shfl_xor(l_pH, 16);
    l_pH += __shfl_xor(l_pH, 32);

    // ---- 2-ticket merge of the two half-blocks ------------------------------
    __syncthreads();
    if (tid == 0) tick = atomicAdd(&cnts[pid], 1);
    __syncthreads();
    const int t = tick;

    if (t == 0) {
        // store partial m, l, and unnormalized O
        if (quad == 0) {
            Ll[pid * 256 + wave * 32 + l16] = l_pL;
            Ll[pid * 256 + wave * 32 + 16 + l16] = l_pH;
        }
        if (lane == 0) Mm[pid * 8 + wave] = m_w;
#pragma unroll
        for (int ti = 0; ti < 16; ti++) {
            const int c = ti * 16 + l16;
#pragma unroll
            for (int h = 0; h < 2; h++) {
                const int nb = q0 + h * 16 + quad * 4;
                f32x4 own = h ? oH[ti] : oL[ti];
                size_t idx = ((size_t)(b * C + c)) * N + nb;
                *(f32x4*)(out + idx) = own;
            }
        }
        __syncthreads();
        if (tid == 0) {
            __threadfence();            // partials visible before release
            atomicExch(&flags[pid], 1);
        }
    } else {
        if (tid == 0) {
            while (atomicAdd(&flags[pid], 0) != 1) __builtin_amdgcn_s_sleep(8);
        }
        __syncthreads();
        __threadfence();                // acquire partner's data

        const float m1 = Mm[pid * 8 + wave];
        const float mt = fmaxf(m1, m_w);
        const float f1 = exp2f(m1 - mt);
        const float f2 = exp2f(m_w - mt);
        const float lnL = Ll[pid * 256 + wave * 32 + l16] * f1 + l_pL * f2;
        const float lnH = Ll[pid * 256 + wave * 32 + 16 + l16] * f1 + l_pH * f2;
        if (quad == 0) {                // redistribute merged l via wave LDS
            Lw[wave][l16] = lnL;
            Lw[wave][16 + l16] = lnH;
        }
        const float g = gamma[0];
        __syncthreads();
        float linv[2][4];
#pragma unroll
        for (int h = 0; h < 2; h++)
#pragma unroll
            for (int r = 0; r < 4; r++)
                linv[h][r] = g / Lw[wave][h * 16 + quad * 4 + r];
#pragma unroll
        for (int ti = 0; ti < 16; ti++) {
            const int c = ti * 16 + l16;
#pragma unroll
            for (int h = 0; h < 2; h++) {
                const int nb = q0 + h * 16 + quad * 4;
                f32x4 own = h ? oH[ti] : oL[ti];
                size_t idx = ((size_t)(b * C + c)) * N + nb;
                f32x4 prev = *(const f32x4*)(out + idx);
                f32x4 xv = *(const f32x4*)(x + idx);
                f32x4 ov;
#pragma unroll
                for (int r = 0; r < 4; r++)
                    ov[r] = (prev[r] * f1 + own[r] * f2) * linv[h][r] + xv[r];
                *(f32x4*)(out + idx) = ov;
            }
        }
    }
}

extern "C" void kernel_launch(void* const* d_in, const int* in_sizes, int n_in,
                              void* d_out, int out_size, void* d_ws, size_t ws_size,
                              hipStream_t stream) {
    const int B = 8, C = 256, N = 4096;
    const float* x     = (const float*)d_in[0];
    const float* wq    = (const float*)d_in[1];
    const float* bq    = (const float*)d_in[2];
    const float* wk    = (const float*)d_in[3];
    const float* bk    = (const float*)d_in[4];
    const float* wv    = (const float*)d_in[5];
    const float* bv    = (const float*)d_in[6];
    const float* gamma = (const float*)d_in[7];
    float* out = (float*)d_out;

    unsigned short* Qc = (unsigned short*)d_ws;             // [B][C][N] bf16 (x log2e), pair-interleaved
    unsigned short* Kr = Qc + (size_t)B * C * N;            // [B][N][C] bf16
    unsigned short* Vc = Kr + (size_t)B * N * C;            // [B][C][N] bf16, pair-interleaved
    unsigned short* Wb = Vc + (size_t)B * C * N;            // [3][256][256] bf16
    int*   cnts  = (int*)(Wb + 196608);                     // [256] (128 used)
    int*   flags = cnts + 256;                              // [256] (128 used)
    float* Mm    = (float*)(flags + 256);                   // [128][8]
    float* Ll    = Mm + 1024;                               // [128][256]

    wcvt_kernel<<<dim3(192), 256, 0, stream>>>(wq, wk, wv, Wb, cnts);
    qkv_kernel<<<dim3(1024), 256, 0, stream>>>(x, Wb, bq, bk, bv, Qc, Kr, Vc);
    attn_kernel<<<dim3(256), 512, 0, stream>>>(Qc, Kr, Vc, x, gamma, out,
                                               cnts, flags, Mm, Ll);
}